// Round 2
// baseline (336.999 us; speedup 1.0000x reference)
//
#include <hip/hip_runtime.h>

// BioREDirect: 3x ragged attention-pool (row-0 attention) + tanh-dense + classifier.
// B=64, S=512, H=768, K=64, labels {9,3,3}. Inputs/outputs are float32 on device
// (reference is pure jnp.float32; bf16-flavored threshold is tolerance only).

#define Hdim 768
#define Kdim 64
#define Sdim 512
#define Bdim 64

__device__ __forceinline__ float wave_sum(float v) {
#pragma unroll
    for (int off = 32; off > 0; off >>= 1) v += __shfl_down(v, off, 64);
    return v;
}

__global__ __launch_bounds__(256) void biored_fused(
    const float* __restrict__ seq,
    const int* __restrict__ idxr, const int* __restrict__ lenr,
    const int* __restrict__ idxn, const int* __restrict__ lenn,
    const int* __restrict__ idxd, const int* __restrict__ lend,
    const float* __restrict__ dWr, const float* __restrict__ dbr,
    const float* __restrict__ cWr, const float* __restrict__ cbr,
    const float* __restrict__ dWn, const float* __restrict__ dbn,
    const float* __restrict__ cWn, const float* __restrict__ cbn,
    const float* __restrict__ dWd, const float* __restrict__ dbd,
    const float* __restrict__ cWd, const float* __restrict__ cbd,
    float* __restrict__ out)
{
    const int b    = blockIdx.x;
    const int g    = blockIdx.y;
    const int tid  = threadIdx.x;
    const int lane = tid & 63;
    const int wave = tid >> 6;

    const int* idxp; const int* lnp;
    const float *dW, *db, *cW, *cb;
    int nlab, outoff;
    if (g == 0)      { idxp = idxr; lnp = lenr; dW = dWr; db = dbr; cW = cWr; cb = cbr; nlab = 9; outoff = 0; }
    else if (g == 1) { idxp = idxn; lnp = lenn; dW = dWn; db = dbn; cW = cWn; cb = cbn; nlab = 3; outoff = Bdim * 9; }
    else             { idxp = idxd; lnp = lend; dW = dWd; db = dbd; cW = cWd; cb = cbd; nlab = 3; outoff = Bdim * 12; }

    __shared__ int   sidx[Kdim];
    __shared__ float attn[Kdim];
    __shared__ __align__(16) float pooled[Hdim];
    __shared__ __align__(16) float hvec[Hdim];

    if (tid < Kdim) sidx[tid] = idxp[b * Kdim + tid];
    const int len = lnp[b];
    __syncthreads();

    // ---- scores: row 0 of G G^T (each wave handles 16 of the 64 j's) ----
    {
        const float* row0 = seq + ((size_t)b * Sdim + sidx[0]) * Hdim;
        float g0[12];
#pragma unroll
        for (int k = 0; k < 3; ++k) {
            float4 v = *(const float4*)(row0 + 4 * lane + 256 * k);
            g0[4 * k + 0] = v.x; g0[4 * k + 1] = v.y;
            g0[4 * k + 2] = v.z; g0[4 * k + 3] = v.w;
        }
        for (int j = wave; j < Kdim; j += 4) {
            const float* rowj = seq + ((size_t)b * Sdim + sidx[j]) * Hdim;
            float acc = 0.f;
#pragma unroll
            for (int k = 0; k < 3; ++k) {
                float4 v = *(const float4*)(rowj + 4 * lane + 256 * k);
                acc += g0[4 * k + 0] * v.x + g0[4 * k + 1] * v.y
                     + g0[4 * k + 2] * v.z + g0[4 * k + 3] * v.w;
            }
            acc = wave_sum(acc);
            if (lane == 0) attn[j] = acc;
        }
    }
    __syncthreads();

    // ---- softmax over K=64 on wave 0 (one lane per j) ----
    if (wave == 0 && len > 0) {
        float s = (lane < len) ? attn[lane] : -1e30f;
        float mx = s;
#pragma unroll
        for (int off = 32; off > 0; off >>= 1) mx = fmaxf(mx, __shfl_xor(mx, off, 64));
        float e = (lane < len) ? __expf(s - mx) : 0.f;
        float sum = e;
#pragma unroll
        for (int off = 32; off > 0; off >>= 1) sum += __shfl_xor(sum, off, 64);
        attn[lane] = e / sum;
    }
    __syncthreads();

    // ---- pooled[h] = sum_j a[j] * G[j][h]  (or fallback seq[b,0]) ----
    if (len > 0) {
        for (int h = tid; h < Hdim; h += 256) {
            float acc = 0.f;
#pragma unroll 8
            for (int j = 0; j < Kdim; ++j) {
                acc += attn[j] * seq[((size_t)b * Sdim + sidx[j]) * Hdim + h];
            }
            pooled[h] = acc;
        }
    } else {
        for (int h = tid; h < Hdim; h += 256)
            pooled[h] = seq[(size_t)b * Sdim * Hdim + h];
    }
    __syncthreads();

    // ---- dense: h = tanh(Wd @ pooled + bd); pooled stripe kept in VGPRs ----
    {
        float p[12];
#pragma unroll
        for (int k = 0; k < 3; ++k) {
            float4 v = *(const float4*)&pooled[4 * lane + 256 * k];
            p[4 * k + 0] = v.x; p[4 * k + 1] = v.y; p[4 * k + 2] = v.z; p[4 * k + 3] = v.w;
        }
        for (int i = wave; i < Hdim; i += 4) {
            const float* wr = dW + (size_t)i * Hdim;
            float acc = 0.f;
#pragma unroll
            for (int k = 0; k < 3; ++k) {
                float4 v = *(const float4*)(wr + 4 * lane + 256 * k);
                acc += p[4 * k + 0] * v.x + p[4 * k + 1] * v.y
                     + p[4 * k + 2] * v.z + p[4 * k + 3] * v.w;
            }
            acc = wave_sum(acc);
            if (lane == 0) hvec[i] = tanhf(acc + db[i]);
        }
    }
    __syncthreads();

    // ---- classifier: logits = Wc @ h + bc  (wave 0) ----
    if (wave == 0) {
        for (int c = 0; c < nlab; ++c) {
            const float* wr = cW + (size_t)c * Hdim;
            float acc = 0.f;
#pragma unroll
            for (int k = 0; k < 3; ++k) {
                float4 v  = *(const float4*)(wr + 4 * lane + 256 * k);
                float4 pv = *(const float4*)&hvec[4 * lane + 256 * k];
                acc += pv.x * v.x + pv.y * v.y + pv.z * v.z + pv.w * v.w;
            }
            acc = wave_sum(acc);
            if (lane == 0)
                out[outoff + b * nlab + c] = acc + cb[c];
        }
    }
}

extern "C" void kernel_launch(void* const* d_in, const int* in_sizes, int n_in,
                              void* d_out, int out_size, void* d_ws, size_t ws_size,
                              hipStream_t stream) {
    const float* seq  = (const float*)d_in[0];
    const int*   idxr = (const int*)d_in[1];
    const int*   lenr = (const int*)d_in[2];
    const int*   idxn = (const int*)d_in[3];
    const int*   lenn = (const int*)d_in[4];
    const int*   idxd = (const int*)d_in[5];
    const int*   lend = (const int*)d_in[6];
    const float* dWr  = (const float*)d_in[7];
    const float* dbr  = (const float*)d_in[8];
    const float* cWr  = (const float*)d_in[9];
    const float* cbr  = (const float*)d_in[10];
    const float* dWn  = (const float*)d_in[11];
    const float* dbn  = (const float*)d_in[12];
    const float* cWn  = (const float*)d_in[13];
    const float* cbn  = (const float*)d_in[14];
    const float* dWd  = (const float*)d_in[15];
    const float* dbd  = (const float*)d_in[16];
    const float* cWd  = (const float*)d_in[17];
    const float* cbd  = (const float*)d_in[18];
    float* out = (float*)d_out;

    dim3 grid(Bdim, 3, 1);
    biored_fused<<<grid, 256, 0, stream>>>(
        seq, idxr, lenr, idxn, lenn, idxd, lend,
        dWr, dbr, cWr, cbr, dWn, dbn, cWn, cbn, dWd, dbd, cWd, cbd,
        out);
}

// Round 3
// 221.932 us; speedup vs baseline: 1.5185x; 1.5185x over previous
//
#include <hip/hip_runtime.h>
#include <math.h>

// BioREDirect: 3-kernel split.
// K1: ragged attention-pool -> pooled[3][64][768] (ws)
// K2: bf16 MFMA GEMM dense+tanh -> hvecT[3][768][64] (ws, transposed for coalescing)
// K3: classifier -> out (rel[64][9], nov[64][3], dir[64][3])
// fp32 I/O; bf16 only inside K2 GEMM (tolerance is bf16-flavored: 1.66e-2).

#define Hdim 768
#define Kdim 64
#define Sdim 512
#define Bdim 64
#define LDK  72   // 64 + 8 pad (bf16 units); keeps b128 16B-aligned, banks even

typedef float f32x4 __attribute__((ext_vector_type(4)));
typedef short bf16x8 __attribute__((ext_vector_type(8)));

__device__ __forceinline__ float wave_sum(float v) {
#pragma unroll
    for (int off = 32; off > 0; off >>= 1) v += __shfl_down(v, off, 64);
    return v;
}

__device__ __forceinline__ unsigned short f2bf(float f) {
    union { float f; unsigned int u; } c; c.f = f;
    unsigned int u = c.u + 0x7FFFu + ((c.u >> 16) & 1u);  // RNE
    return (unsigned short)(u >> 16);
}

// ---------------- K1: attention pooling ----------------
__global__ __launch_bounds__(256) void k_pool(
    const float* __restrict__ seq,
    const int* __restrict__ idxr, const int* __restrict__ lenr,
    const int* __restrict__ idxn, const int* __restrict__ lenn,
    const int* __restrict__ idxd, const int* __restrict__ lend,
    float* __restrict__ pooled)   // [3][64][768]
{
    const int b = blockIdx.x, g = blockIdx.y;
    const int tid = threadIdx.x, lane = tid & 63, wave = tid >> 6;

    const int* idxp = (g == 0) ? idxr : (g == 1) ? idxn : idxd;
    const int* lnp  = (g == 0) ? lenr : (g == 1) ? lenn : lend;

    __shared__ int   sidx[Kdim];
    __shared__ float attn[Kdim];
    __shared__ float wpart[4 * Hdim];

    if (tid < Kdim) sidx[tid] = idxp[b * Kdim + tid];
    const int len = lnp[b];
    __syncthreads();

    // scores: row 0 of G G^T, only j < len needed
    {
        const float* row0 = seq + ((size_t)b * Sdim + sidx[0]) * Hdim;
        float g0[12];
#pragma unroll
        for (int k = 0; k < 3; ++k) {
            float4 v = *(const float4*)(row0 + 4 * lane + 256 * k);
            g0[4 * k + 0] = v.x; g0[4 * k + 1] = v.y;
            g0[4 * k + 2] = v.z; g0[4 * k + 3] = v.w;
        }
        for (int j = wave; j < len; j += 4) {
            const float* rowj = seq + ((size_t)b * Sdim + sidx[j]) * Hdim;
            float acc = 0.f;
#pragma unroll
            for (int k = 0; k < 3; ++k) {
                float4 v = *(const float4*)(rowj + 4 * lane + 256 * k);
                acc += g0[4 * k + 0] * v.x + g0[4 * k + 1] * v.y
                     + g0[4 * k + 2] * v.z + g0[4 * k + 3] * v.w;
            }
            acc = wave_sum(acc);
            if (lane == 0) attn[j] = acc;
        }
    }
    __syncthreads();

    if (wave == 0 && len > 0) {
        float s = (lane < len) ? attn[lane] : -1e30f;
        float mx = s;
#pragma unroll
        for (int off = 32; off > 0; off >>= 1) mx = fmaxf(mx, __shfl_xor(mx, off, 64));
        float e = (lane < len) ? __expf(s - mx) : 0.f;
        float sum = e;
#pragma unroll
        for (int off = 32; off > 0; off >>= 1) sum += __shfl_xor(sum, off, 64);
        attn[lane] = e / sum;
    }
    __syncthreads();

    float* dst = pooled + ((size_t)g * Bdim + b) * Hdim;
    if (len > 0) {
        // j-parallel pooling: wave w covers j in [16w, 16w+16)
        float p[12] = {0,0,0,0,0,0,0,0,0,0,0,0};
        const int j1 = min(wave * 16 + 16, len);
        for (int j = wave * 16; j < j1; ++j) {
            float a = attn[j];
            const float* rowj = seq + ((size_t)b * Sdim + sidx[j]) * Hdim;
#pragma unroll
            for (int k = 0; k < 3; ++k) {
                float4 v = *(const float4*)(rowj + 4 * lane + 256 * k);
                p[4 * k + 0] += a * v.x; p[4 * k + 1] += a * v.y;
                p[4 * k + 2] += a * v.z; p[4 * k + 3] += a * v.w;
            }
        }
#pragma unroll
        for (int k = 0; k < 3; ++k)
            *(float4*)&wpart[wave * Hdim + 4 * lane + 256 * k] =
                make_float4(p[4 * k], p[4 * k + 1], p[4 * k + 2], p[4 * k + 3]);
        __syncthreads();
        for (int h = tid; h < Hdim; h += 256)
            dst[h] = wpart[h] + wpart[Hdim + h] + wpart[2 * Hdim + h] + wpart[3 * Hdim + h];
    } else {
        for (int h = tid; h < Hdim; h += 256)
            dst[h] = seq[(size_t)b * Sdim * Hdim + h];
    }
}

// ---------------- K2: dense + tanh via bf16 MFMA ----------------
// hT[g][i][b] = tanh( sum_k W[i][k] * P[b][k] + db[i] )
__global__ __launch_bounds__(256) void k_dense(
    const float* __restrict__ pooled,   // [3][64][768]
    const float* __restrict__ dWr, const float* __restrict__ dbr,
    const float* __restrict__ dWn, const float* __restrict__ dbn,
    const float* __restrict__ dWd, const float* __restrict__ dbd,
    float* __restrict__ hvecT)          // [3][768][64]
{
    const int mt = blockIdx.x, g = blockIdx.y;
    const float* dW = (g == 0) ? dWr : (g == 1) ? dWn : dWd;
    const float* db = (g == 0) ? dbr : (g == 1) ? dbn : dbd;
    const int i0 = mt * 64;

    const int tid = threadIdx.x, lane = tid & 63, wv = tid >> 6;
    const int q = lane >> 4, col = lane & 15;

    __shared__ unsigned short Ws[64 * LDK];
    __shared__ unsigned short Ps[64 * LDK];

    f32x4 acc[4] = {{0,0,0,0},{0,0,0,0},{0,0,0,0},{0,0,0,0}};

    const int srow  = tid >> 2;        // 0..63
    const int cbase = (tid & 3) * 16;  // 0,16,32,48
    const float* Pg = pooled + (size_t)g * Bdim * Hdim;

    for (int kk = 0; kk < Hdim; kk += 64) {
#pragma unroll
        for (int u = 0; u < 4; ++u) {
            int c = cbase + 4 * u;
            float4 w4 = *(const float4*)(dW + (size_t)(i0 + srow) * Hdim + kk + c);
            float4 p4 = *(const float4*)(Pg + (size_t)srow * Hdim + kk + c);
            ushort4 wb = make_ushort4(f2bf(w4.x), f2bf(w4.y), f2bf(w4.z), f2bf(w4.w));
            ushort4 pb = make_ushort4(f2bf(p4.x), f2bf(p4.y), f2bf(p4.z), f2bf(p4.w));
            *(ushort4*)&Ws[srow * LDK + c] = wb;
            *(ushort4*)&Ps[srow * LDK + c] = pb;
        }
        __syncthreads();
#pragma unroll
        for (int ks = 0; ks < 64; ks += 32) {
            bf16x8 a = *(const bf16x8*)&Ws[(wv * 16 + col) * LDK + ks + 8 * q];
#pragma unroll
            for (int n = 0; n < 4; ++n) {
                bf16x8 bb = *(const bf16x8*)&Ps[(n * 16 + col) * LDK + ks + 8 * q];
                acc[n] = __builtin_amdgcn_mfma_f32_16x16x32_bf16(a, bb, acc[n], 0, 0, 0);
            }
        }
        __syncthreads();
    }

#pragma unroll
    for (int n = 0; n < 4; ++n) {
        int b = n * 16 + col;
#pragma unroll
        for (int r = 0; r < 4; ++r) {
            int i = i0 + wv * 16 + q * 4 + r;
            float v = tanhf(acc[n][r] + db[i]);
            hvecT[((size_t)g * Hdim + i) * Bdim + b] = v;
        }
    }
}

// ---------------- K3: classifier ----------------
__global__ __launch_bounds__(64) void k_cls(
    const float* __restrict__ hvecT,    // [3][768][64]
    const float* __restrict__ cWr, const float* __restrict__ cbr,
    const float* __restrict__ cWn, const float* __restrict__ cbn,
    const float* __restrict__ cWd, const float* __restrict__ cbd,
    float* __restrict__ out)
{
    const int id = blockIdx.x;  // 0..14
    int g, c, nlab, off;
    if (id < 9)       { g = 0; c = id;      nlab = 9; off = 0;   }
    else if (id < 12) { g = 1; c = id - 9;  nlab = 3; off = 576; }
    else              { g = 2; c = id - 12; nlab = 3; off = 768; }
    const float* cW = (g == 0) ? cWr : (g == 1) ? cWn : cWd;
    const float* cb = (g == 0) ? cbr : (g == 1) ? cbn : cbd;

    const int b = threadIdx.x;
    const float* hT = hvecT + (size_t)g * Hdim * Bdim;
    const float* wr = cW + (size_t)c * Hdim;
    float acc = 0.f;
#pragma unroll 16
    for (int i = 0; i < Hdim; ++i)
        acc += wr[i] * hT[i * Bdim + b];
    out[off + b * nlab + c] = acc + cb[c];
}

extern "C" void kernel_launch(void* const* d_in, const int* in_sizes, int n_in,
                              void* d_out, int out_size, void* d_ws, size_t ws_size,
                              hipStream_t stream) {
    const float* seq  = (const float*)d_in[0];
    const int*   idxr = (const int*)d_in[1];
    const int*   lenr = (const int*)d_in[2];
    const int*   idxn = (const int*)d_in[3];
    const int*   lenn = (const int*)d_in[4];
    const int*   idxd = (const int*)d_in[5];
    const int*   lend = (const int*)d_in[6];
    const float* dWr  = (const float*)d_in[7];
    const float* dbr  = (const float*)d_in[8];
    const float* cWr  = (const float*)d_in[9];
    const float* cbr  = (const float*)d_in[10];
    const float* dWn  = (const float*)d_in[11];
    const float* dbn  = (const float*)d_in[12];
    const float* cWn  = (const float*)d_in[13];
    const float* cbn  = (const float*)d_in[14];
    const float* dWd  = (const float*)d_in[15];
    const float* dbd  = (const float*)d_in[16];
    const float* cWd  = (const float*)d_in[17];
    const float* cbd  = (const float*)d_in[18];
    float* out = (float*)d_out;

    float* pooled = (float*)d_ws;                       // 3*64*768 f32 = 589,824 B
    float* hvecT  = pooled + 3 * Bdim * Hdim;           // 3*768*64 f32 = 589,824 B

    k_pool<<<dim3(Bdim, 3), 256, 0, stream>>>(seq, idxr, lenr, idxn, lenn, idxd, lend, pooled);
    k_dense<<<dim3(Hdim / 64, 3), 256, 0, stream>>>(pooled, dWr, dbr, dWn, dbn, dWd, dbd, hvecT);
    k_cls<<<15, 64, 0, stream>>>(hvecT, cWr, cbr, cWn, cbn, cWd, cbd, out);
}

// Round 4
// 197.493 us; speedup vs baseline: 1.7064x; 1.1237x over previous
//
#include <hip/hip_runtime.h>
#include <math.h>

// BioREDirect: 3-kernel split.
// K1 (1024 thr): ragged attention-pool -> pooled[3][64][768] (ws)
// K2 (256 thr): bf16 MFMA GEMM dense+tanh -> hvecT[3][768][64] (ws)
// K3 (256 thr): classifier -> out (rel[64][9], nov[64][3], dir[64][3])
// fp32 I/O; bf16 only inside K2 GEMM (tolerance is bf16-flavored: 1.66e-2).
// NOTE: timed iteration includes ~150us of harness restore/poison fills
// (402 MB ws poison at 60us x N) — kernel-side floor is all we control.

#define Hdim 768
#define Kdim 64
#define Sdim 512
#define Bdim 64
#define LDK  72   // 64 + 8 pad (bf16 units); keeps b128 16B-aligned, banks even

typedef float f32x4 __attribute__((ext_vector_type(4)));
typedef short bf16x8 __attribute__((ext_vector_type(8)));

__device__ __forceinline__ float wave_sum(float v) {
#pragma unroll
    for (int off = 32; off > 0; off >>= 1) v += __shfl_down(v, off, 64);
    return v;
}

__device__ __forceinline__ unsigned short f2bf(float f) {
    union { float f; unsigned int u; } c; c.f = f;
    unsigned int u = c.u + 0x7FFFu + ((c.u >> 16) & 1u);  // RNE
    return (unsigned short)(u >> 16);
}

// ---------------- K1: attention pooling (16 waves/block) ----------------
__global__ __launch_bounds__(1024) void k_pool(
    const float* __restrict__ seq,
    const int* __restrict__ idxr, const int* __restrict__ lenr,
    const int* __restrict__ idxn, const int* __restrict__ lenn,
    const int* __restrict__ idxd, const int* __restrict__ lend,
    float* __restrict__ pooled)   // [3][64][768]
{
    const int b = blockIdx.x, g = blockIdx.y;
    const int tid = threadIdx.x, lane = tid & 63, wave = tid >> 6;  // wave 0..15

    const int* idxp = (g == 0) ? idxr : (g == 1) ? idxn : idxd;
    const int* lnp  = (g == 0) ? lenr : (g == 1) ? lenn : lend;

    __shared__ int   sidx[Kdim];
    __shared__ float attn[Kdim];
    __shared__ float wpart[16 * Hdim];   // 48 KB

    if (tid < Kdim) sidx[tid] = idxp[b * Kdim + tid];
    const int len = lnp[b];
    __syncthreads();

    // scores: row 0 of G G^T, only j < len needed; 16 waves stride j
    {
        const float* row0 = seq + ((size_t)b * Sdim + sidx[0]) * Hdim;
        float g0[12];
#pragma unroll
        for (int k = 0; k < 3; ++k) {
            float4 v = *(const float4*)(row0 + 4 * lane + 256 * k);
            g0[4 * k + 0] = v.x; g0[4 * k + 1] = v.y;
            g0[4 * k + 2] = v.z; g0[4 * k + 3] = v.w;
        }
        for (int j = wave; j < len; j += 16) {
            const float* rowj = seq + ((size_t)b * Sdim + sidx[j]) * Hdim;
            float acc = 0.f;
#pragma unroll
            for (int k = 0; k < 3; ++k) {
                float4 v = *(const float4*)(rowj + 4 * lane + 256 * k);
                acc += g0[4 * k + 0] * v.x + g0[4 * k + 1] * v.y
                     + g0[4 * k + 2] * v.z + g0[4 * k + 3] * v.w;
            }
            acc = wave_sum(acc);
            if (lane == 0) attn[j] = acc;
        }
    }
    __syncthreads();

    if (wave == 0 && len > 0) {
        float s = (lane < len) ? attn[lane] : -1e30f;
        float mx = s;
#pragma unroll
        for (int off = 32; off > 0; off >>= 1) mx = fmaxf(mx, __shfl_xor(mx, off, 64));
        float e = (lane < len) ? __expf(s - mx) : 0.f;
        float sum = e;
#pragma unroll
        for (int off = 32; off > 0; off >>= 1) sum += __shfl_xor(sum, off, 64);
        attn[lane] = e / sum;
    }
    __syncthreads();

    float* dst = pooled + ((size_t)g * Bdim + b) * Hdim;
    if (len > 0) {
        // j-parallel pooling: wave w covers j in [4w, 4w+4)
        float p[12] = {0,0,0,0,0,0,0,0,0,0,0,0};
        const int j1 = min(wave * 4 + 4, len);
        for (int j = wave * 4; j < j1; ++j) {
            float a = attn[j];
            const float* rowj = seq + ((size_t)b * Sdim + sidx[j]) * Hdim;
#pragma unroll
            for (int k = 0; k < 3; ++k) {
                float4 v = *(const float4*)(rowj + 4 * lane + 256 * k);
                p[4 * k + 0] += a * v.x; p[4 * k + 1] += a * v.y;
                p[4 * k + 2] += a * v.z; p[4 * k + 3] += a * v.w;
            }
        }
#pragma unroll
        for (int k = 0; k < 3; ++k)
            *(float4*)&wpart[wave * Hdim + 4 * lane + 256 * k] =
                make_float4(p[4 * k], p[4 * k + 1], p[4 * k + 2], p[4 * k + 3]);
        __syncthreads();
        if (tid < Hdim) {
            float acc = 0.f;
#pragma unroll
            for (int w = 0; w < 16; ++w) acc += wpart[w * Hdim + tid];
            dst[tid] = acc;
        }
    } else {
        if (tid < Hdim) dst[tid] = seq[(size_t)b * Sdim * Hdim + tid];
    }
}

// ---------------- K2: dense + tanh via bf16 MFMA ----------------
// hT[g][i][b] = tanh( sum_k W[i][k] * P[b][k] + db[i] )
__global__ __launch_bounds__(256) void k_dense(
    const float* __restrict__ pooled,   // [3][64][768]
    const float* __restrict__ dWr, const float* __restrict__ dbr,
    const float* __restrict__ dWn, const float* __restrict__ dbn,
    const float* __restrict__ dWd, const float* __restrict__ dbd,
    float* __restrict__ hvecT)          // [3][768][64]
{
    const int mt = blockIdx.x, g = blockIdx.y;
    const float* dW = (g == 0) ? dWr : (g == 1) ? dWn : dWd;
    const float* db = (g == 0) ? dbr : (g == 1) ? dbn : dbd;
    const int i0 = mt * 64;

    const int tid = threadIdx.x, lane = tid & 63, wv = tid >> 6;
    const int q = lane >> 4, col = lane & 15;

    __shared__ unsigned short Ws[64 * LDK];
    __shared__ unsigned short Ps[64 * LDK];

    f32x4 acc[4] = {{0,0,0,0},{0,0,0,0},{0,0,0,0},{0,0,0,0}};

    const int srow  = tid >> 2;        // 0..63
    const int cbase = (tid & 3) * 16;  // 0,16,32,48
    const float* Pg = pooled + (size_t)g * Bdim * Hdim;

    for (int kk = 0; kk < Hdim; kk += 64) {
#pragma unroll
        for (int u = 0; u < 4; ++u) {
            int c = cbase + 4 * u;
            float4 w4 = *(const float4*)(dW + (size_t)(i0 + srow) * Hdim + kk + c);
            float4 p4 = *(const float4*)(Pg + (size_t)srow * Hdim + kk + c);
            ushort4 wb = make_ushort4(f2bf(w4.x), f2bf(w4.y), f2bf(w4.z), f2bf(w4.w));
            ushort4 pb = make_ushort4(f2bf(p4.x), f2bf(p4.y), f2bf(p4.z), f2bf(p4.w));
            *(ushort4*)&Ws[srow * LDK + c] = wb;
            *(ushort4*)&Ps[srow * LDK + c] = pb;
        }
        __syncthreads();
#pragma unroll
        for (int ks = 0; ks < 64; ks += 32) {
            bf16x8 a = *(const bf16x8*)&Ws[(wv * 16 + col) * LDK + ks + 8 * q];
#pragma unroll
            for (int n = 0; n < 4; ++n) {
                bf16x8 bb = *(const bf16x8*)&Ps[(n * 16 + col) * LDK + ks + 8 * q];
                acc[n] = __builtin_amdgcn_mfma_f32_16x16x32_bf16(a, bb, acc[n], 0, 0, 0);
            }
        }
        __syncthreads();
    }

#pragma unroll
    for (int n = 0; n < 4; ++n) {
        int b = n * 16 + col;
#pragma unroll
        for (int r = 0; r < 4; ++r) {
            int i = i0 + wv * 16 + q * 4 + r;
            float v = tanhf(acc[n][r] + db[i]);
            hvecT[((size_t)g * Hdim + i) * Bdim + b] = v;
        }
    }
}

// ---------------- K3: classifier (64 b x 4 i-chunks) ----------------
__global__ __launch_bounds__(256) void k_cls(
    const float* __restrict__ hvecT,    // [3][768][64]
    const float* __restrict__ cWr, const float* __restrict__ cbr,
    const float* __restrict__ cWn, const float* __restrict__ cbn,
    const float* __restrict__ cWd, const float* __restrict__ cbd,
    float* __restrict__ out)
{
    const int id = blockIdx.x;  // 0..14
    int g, c, nlab, off;
    if (id < 9)       { g = 0; c = id;      nlab = 9; off = 0;   }
    else if (id < 12) { g = 1; c = id - 9;  nlab = 3; off = 576; }
    else              { g = 2; c = id - 12; nlab = 3; off = 768; }
    const float* cW = (g == 0) ? cWr : (g == 1) ? cWn : cWd;
    const float* cb = (g == 0) ? cbr : (g == 1) ? cbn : cbd;

    const int b = threadIdx.x & 63;
    const int chunk = threadIdx.x >> 6;    // 0..3, 192 i's each
    const float* hT = hvecT + (size_t)g * Hdim * Bdim;
    const float* wr = cW + (size_t)c * Hdim;

    float acc = 0.f;
    const int ibase = chunk * 192;
#pragma unroll 16
    for (int i = ibase; i < ibase + 192; ++i)
        acc += wr[i] * hT[i * Bdim + b];

    __shared__ float red[4][Bdim];
    red[chunk][b] = acc;
    __syncthreads();
    if (chunk == 0)
        out[off + b * nlab + c] = red[0][b] + red[1][b] + red[2][b] + red[3][b] + cb[c];
}

extern "C" void kernel_launch(void* const* d_in, const int* in_sizes, int n_in,
                              void* d_out, int out_size, void* d_ws, size_t ws_size,
                              hipStream_t stream) {
    const float* seq  = (const float*)d_in[0];
    const int*   idxr = (const int*)d_in[1];
    const int*   lenr = (const int*)d_in[2];
    const int*   idxn = (const int*)d_in[3];
    const int*   lenn = (const int*)d_in[4];
    const int*   idxd = (const int*)d_in[5];
    const int*   lend = (const int*)d_in[6];
    const float* dWr  = (const float*)d_in[7];
    const float* dbr  = (const float*)d_in[8];
    const float* cWr  = (const float*)d_in[9];
    const float* cbr  = (const float*)d_in[10];
    const float* dWn  = (const float*)d_in[11];
    const float* dbn  = (const float*)d_in[12];
    const float* cWn  = (const float*)d_in[13];
    const float* cbn  = (const float*)d_in[14];
    const float* dWd  = (const float*)d_in[15];
    const float* dbd  = (const float*)d_in[16];
    const float* cWd  = (const float*)d_in[17];
    const float* cbd  = (const float*)d_in[18];
    float* out = (float*)d_out;

    float* pooled = (float*)d_ws;                       // 3*64*768 f32
    float* hvecT  = pooled + 3 * Bdim * Hdim;           // 3*768*64 f32

    k_pool<<<dim3(Bdim, 3), 1024, 0, stream>>>(seq, idxr, lenr, idxn, lenn, idxd, lend, pooled);
    k_dense<<<dim3(Hdim / 64, 3), 256, 0, stream>>>(pooled, dWr, dbr, dWn, dbn, dWd, dbd, hvecT);
    k_cls<<<15, 256, 0, stream>>>(hvecT, cWr, cbr, cWn, cbn, cWd, cbd, out);
}

// Round 5
// 189.062 us; speedup vs baseline: 1.7825x; 1.0446x over previous
//
#include <hip/hip_runtime.h>
#include <math.h>

// BioREDirect, 2-kernel version.
// K1 (1024 thr): ragged attention-pool, ONLINE softmax single-pass over gathered
//     rows (row kept in regs between score and accumulate) -> pooled[3][64][768].
//     Blocks with b==0 also init out[] with classifier biases.
// K2 (256 thr): bf16 MFMA dense+tanh; h-tile round-trips LDS; classifier partials
//     atomicAdd'ed straight into out. No K3, no hvecT.
// fp32 I/O; bf16 only inside K2 GEMM (tolerance is bf16-flavored: 1.66e-2).
// NOTE: timed iteration carries ~149us of harness restore/poison fills (fixed).

#define Hdim 768
#define Kdim 64
#define Sdim 512
#define Bdim 64
#define LDK  72   // 64 + 8 pad (bf16 units); keeps b128 16B-aligned, banks even

typedef float f32x4 __attribute__((ext_vector_type(4)));
typedef short bf16x8 __attribute__((ext_vector_type(8)));

__device__ __forceinline__ unsigned short f2bf(float f) {
    union { float f; unsigned int u; } c; c.f = f;
    unsigned int u = c.u + 0x7FFFu + ((c.u >> 16) & 1u);  // RNE
    return (unsigned short)(u >> 16);
}

// ---------------- K1: online-softmax attention pooling (16 waves) ----------------
__global__ __launch_bounds__(1024) void k_pool(
    const float* __restrict__ seq,
    const int* __restrict__ idxr, const int* __restrict__ lenr,
    const int* __restrict__ idxn, const int* __restrict__ lenn,
    const int* __restrict__ idxd, const int* __restrict__ lend,
    const float* __restrict__ cbr, const float* __restrict__ cbn,
    const float* __restrict__ cbd,
    float* __restrict__ pooled,   // [3][64][768]
    float* __restrict__ out)      // bias-init here; K2 atomicAdds partials
{
    const int b = blockIdx.x, g = blockIdx.y;
    const int tid = threadIdx.x, lane = tid & 63, wave = tid >> 6;  // 16 waves

    const int* idxp = (g == 0) ? idxr : (g == 1) ? idxn : idxd;
    const int* lnp  = (g == 0) ? lenr : (g == 1) ? lenn : lend;

    __shared__ int   sidx[Kdim];
    __shared__ float wm[16], wl[16], coef[16];
    __shared__ float wpart[16][Hdim];   // 48 KB

    if (tid < Kdim) sidx[tid] = idxp[b * Kdim + tid];
    const int len = lnp[b];

    // bias-init of out (before K2's atomics; K2 is stream-ordered after K1)
    if (b == 0) {
        if (g == 0)      { if (tid < 576) out[tid]       = cbr[tid % 9]; }
        else if (g == 1) { if (tid < 192) out[576 + tid] = cbn[tid % 3]; }
        else             { if (tid < 192) out[768 + tid] = cbd[tid % 3]; }
    }
    __syncthreads();

    float* dst = pooled + ((size_t)g * Bdim + b) * Hdim;

    if (len > 0) {
        const float* row0 = seq + ((size_t)b * Sdim + sidx[0]) * Hdim;
        float g0[12];
#pragma unroll
        for (int k = 0; k < 3; ++k) {
            float4 v = *(const float4*)(row0 + 4 * lane + 256 * k);
            g0[4 * k + 0] = v.x; g0[4 * k + 1] = v.y;
            g0[4 * k + 2] = v.z; g0[4 * k + 3] = v.w;
        }

        float m = -1e30f, l = 0.f;
        float p[12] = {0,0,0,0,0,0,0,0,0,0,0,0};

        for (int j = wave; j < len; j += 16) {
            const float* rowj = seq + ((size_t)b * Sdim + sidx[j]) * Hdim;
            float v[12];
#pragma unroll
            for (int k = 0; k < 3; ++k) {
                float4 t = *(const float4*)(rowj + 4 * lane + 256 * k);
                v[4 * k + 0] = t.x; v[4 * k + 1] = t.y;
                v[4 * k + 2] = t.z; v[4 * k + 3] = t.w;
            }
            float s = 0.f;
#pragma unroll
            for (int k = 0; k < 12; ++k) s += g0[k] * v[k];
#pragma unroll
            for (int off = 32; off > 0; off >>= 1) s += __shfl_xor(s, off, 64);

            float mn    = fmaxf(m, s);
            float scale = __expf(m - mn);
            float e     = __expf(s - mn);
            l = l * scale + e;
#pragma unroll
            for (int k = 0; k < 12; ++k) p[k] = p[k] * scale + e * v[k];
            m = mn;
        }

        if (lane == 0) { wm[wave] = m; wl[wave] = l; }
#pragma unroll
        for (int k = 0; k < 3; ++k)
            *(float4*)&wpart[wave][4 * lane + 256 * k] =
                make_float4(p[4 * k], p[4 * k + 1], p[4 * k + 2], p[4 * k + 3]);
        __syncthreads();

        if (wave == 0 && lane < 16) {
            float mw = wm[lane], lw = wl[lane];
            float M = mw;
#pragma unroll
            for (int off = 8; off > 0; off >>= 1) M = fmaxf(M, __shfl_xor(M, off, 64));
            float sc = __expf(mw - M);        // 0 for waves with no j (mw=-1e30)
            float Ls = lw * sc;
#pragma unroll
            for (int off = 8; off > 0; off >>= 1) Ls += __shfl_xor(Ls, off, 64);
            coef[lane] = sc / Ls;
        }
        __syncthreads();

        if (tid < Hdim) {
            float acc = 0.f;
#pragma unroll
            for (int w = 0; w < 16; ++w) acc += wpart[w][tid] * coef[w];
            dst[tid] = acc;
        }
    } else {
        if (tid < Hdim) dst[tid] = seq[(size_t)b * Sdim * Hdim + tid];
    }
}

// ---------------- K2: dense+tanh (bf16 MFMA) + fused classifier ----------------
__global__ __launch_bounds__(256) void k_dense_cls(
    const float* __restrict__ pooled,   // [3][64][768]
    const float* __restrict__ dWr, const float* __restrict__ dbr,
    const float* __restrict__ cWr,
    const float* __restrict__ dWn, const float* __restrict__ dbn,
    const float* __restrict__ cWn,
    const float* __restrict__ dWd, const float* __restrict__ dbd,
    const float* __restrict__ cWd,
    float* __restrict__ out)
{
    const int mt = blockIdx.x, g = blockIdx.y;
    const float *dW, *db, *cW; int nlab, off;
    if (g == 0)      { dW = dWr; db = dbr; cW = cWr; nlab = 9; off = 0;   }
    else if (g == 1) { dW = dWn; db = dbn; cW = cWn; nlab = 3; off = 576; }
    else             { dW = dWd; db = dbd; cW = cWd; nlab = 3; off = 768; }
    const int i0 = mt * 64;

    const int tid = threadIdx.x, lane = tid & 63, wv = tid >> 6;
    const int q = lane >> 4, col = lane & 15;

    __shared__ unsigned short Ws[64 * LDK];
    __shared__ unsigned short Ps[64 * LDK];
    __shared__ float hs[64][65];

    f32x4 acc[4] = {{0,0,0,0},{0,0,0,0},{0,0,0,0},{0,0,0,0}};

    const int srow  = tid >> 2;        // 0..63
    const int cbase = (tid & 3) * 16;  // 0,16,32,48
    const float* Pg = pooled + (size_t)g * Bdim * Hdim;

    for (int kk = 0; kk < Hdim; kk += 64) {
#pragma unroll
        for (int u = 0; u < 4; ++u) {
            int c = cbase + 4 * u;
            float4 w4 = *(const float4*)(dW + (size_t)(i0 + srow) * Hdim + kk + c);
            float4 p4 = *(const float4*)(Pg + (size_t)srow * Hdim + kk + c);
            *(ushort4*)&Ws[srow * LDK + c] = make_ushort4(f2bf(w4.x), f2bf(w4.y), f2bf(w4.z), f2bf(w4.w));
            *(ushort4*)&Ps[srow * LDK + c] = make_ushort4(f2bf(p4.x), f2bf(p4.y), f2bf(p4.z), f2bf(p4.w));
        }
        __syncthreads();
#pragma unroll
        for (int ks = 0; ks < 64; ks += 32) {
            bf16x8 a = *(const bf16x8*)&Ws[(wv * 16 + col) * LDK + ks + 8 * q];
#pragma unroll
            for (int n = 0; n < 4; ++n) {
                bf16x8 bb = *(const bf16x8*)&Ps[(n * 16 + col) * LDK + ks + 8 * q];
                acc[n] = __builtin_amdgcn_mfma_f32_16x16x32_bf16(a, bb, acc[n], 0, 0, 0);
            }
        }
        __syncthreads();
    }

    // epilogue: tanh+bias -> LDS h-tile [i_local][b]
#pragma unroll
    for (int n = 0; n < 4; ++n) {
        int bb = n * 16 + col;
#pragma unroll
        for (int r = 0; r < 4; ++r) {
            int il = wv * 16 + q * 4 + r;
            hs[il][bb] = tanhf(acc[n][r] + db[i0 + il]);
        }
    }
    __syncthreads();

    // classifier partial for this i-tile: out[b][c] += sum_il cW[c][i0+il]*h[il][b]
    for (int c = wv; c < nlab; c += 4) {
        const float* wr = cW + (size_t)c * Hdim + i0;
        float a = 0.f;
#pragma unroll 16
        for (int il = 0; il < 64; ++il)
            a += wr[il] * hs[il][lane];
        atomicAdd(&out[off + lane * nlab + c], a);
    }
}

extern "C" void kernel_launch(void* const* d_in, const int* in_sizes, int n_in,
                              void* d_out, int out_size, void* d_ws, size_t ws_size,
                              hipStream_t stream) {
    const float* seq  = (const float*)d_in[0];
    const int*   idxr = (const int*)d_in[1];
    const int*   lenr = (const int*)d_in[2];
    const int*   idxn = (const int*)d_in[3];
    const int*   lenn = (const int*)d_in[4];
    const int*   idxd = (const int*)d_in[5];
    const int*   lend = (const int*)d_in[6];
    const float* dWr  = (const float*)d_in[7];
    const float* dbr  = (const float*)d_in[8];
    const float* cWr  = (const float*)d_in[9];
    const float* cbr  = (const float*)d_in[10];
    const float* dWn  = (const float*)d_in[11];
    const float* dbn  = (const float*)d_in[12];
    const float* cWn  = (const float*)d_in[13];
    const float* cbn  = (const float*)d_in[14];
    const float* dWd  = (const float*)d_in[15];
    const float* dbd  = (const float*)d_in[16];
    const float* cWd  = (const float*)d_in[17];
    const float* cbd  = (const float*)d_in[18];
    float* out = (float*)d_out;

    float* pooled = (float*)d_ws;   // 3*64*768 f32

    k_pool<<<dim3(Bdim, 3), 1024, 0, stream>>>(
        seq, idxr, lenr, idxn, lenn, idxd, lend, cbr, cbn, cbd, pooled, out);
    k_dense_cls<<<dim3(Hdim / 64, 3), 256, 0, stream>>>(
        pooled, dWr, dbr, cWr, dWn, dbn, cWn, dWd, dbd, cWd, out);
}